// Round 5
// baseline (543.762 us; speedup 1.0000x reference)
//
#include <hip/hip_runtime.h>
#include <hip/hip_bf16.h>

#define BB 4
#define SS 512
#define DD 512
#define HH 8
#define DK 64
#define PP 16
#define TSZ 33   // 2P+1

typedef __bf16 bf16x8 __attribute__((ext_vector_type(8)));
typedef __bf16 bf16x4 __attribute__((ext_vector_type(4)));
typedef float  f32x4  __attribute__((ext_vector_type(4)));

union U8 { bf16x8 v; int u[4]; };

__device__ inline bf16x8 cvt8(const float* __restrict__ p) {
    f32x4 a = *(const f32x4*)p;
    f32x4 b = *(const f32x4*)(p + 4);
    bf16x8 r;
    r[0] = (__bf16)a[0]; r[1] = (__bf16)a[1]; r[2] = (__bf16)a[2]; r[3] = (__bf16)a[3];
    r[4] = (__bf16)b[0]; r[5] = (__bf16)b[1]; r[6] = (__bf16)b[2]; r[7] = (__bf16)b[3];
    return r;
}

// ---------------- prep: z=0,1,2 QKV proj (MFMA); z=3 Wo->bf16 + table mean ---------
__global__ void prep_kernel(const float* __restrict__ X0, const float* __restrict__ X1,
                            const float* __restrict__ X2,
                            const float* __restrict__ W0, const float* __restrict__ W1,
                            const float* __restrict__ W2,
                            const float* __restrict__ B0, const float* __restrict__ B1,
                            const float* __restrict__ B2,
                            __bf16* __restrict__ O0, __bf16* __restrict__ O1,
                            __bf16* __restrict__ O2,
                            const float* __restrict__ Wo, __bf16* __restrict__ Wo_bf,
                            const float* __restrict__ rel_table, float* __restrict__ Tm) {
    int z = blockIdx.z;
    int lane = threadIdx.x, wave = threadIdx.y;
    if (z == 3) {
        int bid = blockIdx.y * 32 + blockIdx.x;     // 0..1023
        int t = wave * 64 + lane;                   // 0..255
        int idx = bid * 256 + t;                    // 0..262143 == 512*512
        Wo_bf[idx] = (__bf16)Wo[idx];
        if (bid == 0 && t < TSZ) {
            float s = 0.f;
            for (int e = 0; e < DK; ++e) s += rel_table[t * DK + e];
            Tm[t] = s * (1.f / DK);
        }
        return;
    }
    const float* X = (z == 0) ? X0 : (z == 1) ? X1 : X2;
    const float* W = (z == 0) ? W0 : (z == 1) ? W1 : W2;
    const float* bias = (z == 0) ? B0 : (z == 1) ? B1 : B2;
    __bf16* out = (z == 0) ? O0 : (z == 1) ? O1 : O2;
    int mode = (z == 2);

    int tm = blockIdx.y * 4 + wave;
    int tn = blockIdx.x;
    int m = lane & 15, quad = lane >> 4;

    const float* arow = X + (size_t)(tm * 16 + m) * DD + quad * 8;
    const float* brow = W + (size_t)(tn * 16 + m) * DD + quad * 8;

    f32x4 acc = {0.f, 0.f, 0.f, 0.f};
    for (int k0 = 0; k0 < DD; k0 += 32) {
        bf16x8 a = cvt8(arow + k0);
        bf16x8 b = cvt8(brow + k0);
        acc = __builtin_amdgcn_mfma_f32_16x16x32_bf16(a, b, acc, 0, 0, 0);
    }

    int col = tn * 16 + m;
    int h = col >> 6, dk = col & (DK - 1);
    float bv = bias[col];
#pragma unroll
    for (int r = 0; r < 4; ++r) {
        int rowg = tm * 16 + quad * 4 + r;
        int b = rowg >> 9, i = rowg & (SS - 1);
        float v = acc[r] + bv;
        if (mode == 0)
            out[((size_t)(b * HH + h) * SS + i) * DK + dk] = (__bf16)v;
        else
            out[((size_t)(b * HH + h) * DK + dk) * SS + i] = (__bf16)v;
    }
}

// ---------------- F1: scores + relbias + FULL softmax, final attn f32 -------------
// grid (i0=64, b=4) = 256 blocks, block (64,8).
// Bias: wave w handles j-tiles {w*4..w*4+3}, all 8 h, 8 i-rows. One barrier.
// Scores/softmax: wave w = head w over full 512 j.
__launch_bounds__(512, 2)
__global__ void f1_kernel(const __bf16* __restrict__ Qbf, const __bf16* __restrict__ Kbf,
                          const int* __restrict__ relpos, const float* __restrict__ Tm,
                          const int* __restrict__ mask, float* __restrict__ attn) {
    __shared__ __bf16 bias_sh[8 * 8 * 520];   // [h][i][520j] = 66,560 B

    int l = threadIdx.x, w = threadIdx.y;
    int i0 = blockIdx.x, b = blockIdx.y;
    int I0 = i0 * 8;
    int m = l & 15, quad = l >> 4;

    // Tmean LUT as bf16 bits in registers (lanes 0..32)
    float tmf = Tm[l < TSZ ? l : 0];
    int tmb = (int)__builtin_bit_cast(unsigned short, (__bf16)tmf);

    // ---- bias phase ----
    {
        // unit = tt*8 + i; addr(i,tt) for this lane:
        //   relpos + ((b*SS + I0+i)*SS + (w*4+tt)*16 + m)*DK + quad*8
        const int* p0 = relpos + ((size_t)(b * SS + I0) * SS + (w * 4) * 16 + m) * DK + quad * 8;
        int4 u0 = *(const int4*)(p0);
        int4 u1 = *(const int4*)(p0 + 4);
        int4 u2 = *(const int4*)(p0 + 32);
        int4 u3 = *(const int4*)(p0 + 36);
        for (int unit = 0; unit < 32; ++unit) {
            int tt = unit >> 3, i = unit & 7;
            int4 n0, n1, n2, n3;
            if (unit < 31) {
                int t2 = (unit + 1) >> 3, i2 = (unit + 1) & 7;
                const int* np = relpos + ((size_t)(b * SS + I0 + i2) * SS + (w * 4 + t2) * 16 + m) * DK + quad * 8;
                n0 = *(const int4*)(np);
                n1 = *(const int4*)(np + 4);
                n2 = *(const int4*)(np + 32);
                n3 = *(const int4*)(np + 36);
            }
            const __bf16* qp = Qbf + ((size_t)(b * HH + (m & 7)) * SS + I0 + i) * DK + quad * 8;
            bf16x8 A0 = *(const bf16x8*)qp;
            bf16x8 A1 = *(const bf16x8*)(qp + 32);
#define LUT(vv) __builtin_amdgcn_ds_bpermute((min(max((vv), -PP), PP) + PP) << 2, tmb)
            U8 Bf0, Bf1;
            Bf0.u[0] = LUT(u0.x) | (LUT(u0.y) << 16);
            Bf0.u[1] = LUT(u0.z) | (LUT(u0.w) << 16);
            Bf0.u[2] = LUT(u1.x) | (LUT(u1.y) << 16);
            Bf0.u[3] = LUT(u1.z) | (LUT(u1.w) << 16);
            Bf1.u[0] = LUT(u2.x) | (LUT(u2.y) << 16);
            Bf1.u[1] = LUT(u2.z) | (LUT(u2.w) << 16);
            Bf1.u[2] = LUT(u3.x) | (LUT(u3.y) << 16);
            Bf1.u[3] = LUT(u3.z) | (LUT(u3.w) << 16);
#undef LUT
            f32x4 accB = {0.f, 0.f, 0.f, 0.f};
            accB = __builtin_amdgcn_mfma_f32_16x16x32_bf16(A0, Bf0.v, accB, 0, 0, 0);
            accB = __builtin_amdgcn_mfma_f32_16x16x32_bf16(A1, Bf1.v, accB, 0, 0, 0);
            if (quad < 2) {
#pragma unroll
                for (int r = 0; r < 4; ++r) {
                    int h = quad * 4 + r;
                    bias_sh[(h * 8 + i) * 520 + w * 64 + tt * 16 + m] = (__bf16)accB[r];
                }
            }
            u0 = n0; u1 = n1; u2 = n2; u3 = n3;
        }
    }

    // ---- scores: head w, full j. A rows 8..15 duplicate 0..7. ----
    const __bf16* qrow = Qbf + ((size_t)(b * HH + w) * SS + I0 + (m & 7)) * DK + quad * 8;
    bf16x8 a0 = *(const bf16x8*)qrow;
    bf16x8 a1 = *(const bf16x8*)(qrow + 32);

    f32x4 acc[32];
#pragma unroll
    for (int jt = 0; jt < 32; ++jt) {
        const __bf16* krow = Kbf + ((size_t)(b * HH + w) * SS + jt * 16 + m) * DK + quad * 8;
        bf16x8 b0 = *(const bf16x8*)krow;
        bf16x8 b1 = *(const bf16x8*)(krow + 32);
        f32x4 c = {0.f, 0.f, 0.f, 0.f};
        c = __builtin_amdgcn_mfma_f32_16x16x32_bf16(a0, b0, c, 0, 0, 0);
        c = __builtin_amdgcn_mfma_f32_16x16x32_bf16(a1, b1, c, 0, 0, 0);
        acc[jt] = c;
    }

    __syncthreads();   // bias_sh ready

    // ---- combine + mask ----
    int iLDS = (quad & 1) * 4;   // rows 8..15 mirror 0..7
#pragma unroll
    for (int jt = 0; jt < 32; ++jt) {
        int mv = mask[b * SS + jt * 16 + m];
#pragma unroll
        for (int r = 0; r < 4; ++r) {
            float bv = (float)bias_sh[(w * 8 + iLDS + r) * 520 + jt * 16 + m];
            float v = acc[jt][r] * 0.125f + bv;
            acc[jt][r] = (mv == 0) ? -1e9f : v;
        }
    }

    // ---- full softmax per row ----
    float inv[4];
#pragma unroll
    for (int r = 0; r < 4; ++r) {
        float mx = -1e30f;
#pragma unroll
        for (int jt = 0; jt < 32; ++jt) mx = fmaxf(mx, acc[jt][r]);
        mx = fmaxf(mx, __shfl_xor(mx, 1));
        mx = fmaxf(mx, __shfl_xor(mx, 2));
        mx = fmaxf(mx, __shfl_xor(mx, 4));
        mx = fmaxf(mx, __shfl_xor(mx, 8));
        float sum = 0.f;
#pragma unroll
        for (int jt = 0; jt < 32; ++jt) {
            float e = __expf(acc[jt][r] - mx);
            acc[jt][r] = e;
            sum += e;
        }
        sum += __shfl_xor(sum, 1);
        sum += __shfl_xor(sum, 2);
        sum += __shfl_xor(sum, 4);
        sum += __shfl_xor(sum, 8);
        inv[r] = 1.f / sum;
    }

    // ---- write final normalized attn (quad<2 only; rows 8..15 are dups) ----
    if (quad < 2) {
#pragma unroll
        for (int jt = 0; jt < 32; ++jt) {
#pragma unroll
            for (int r = 0; r < 4; ++r) {
                attn[((size_t)(b * HH + w) * SS + I0 + quad * 4 + r) * SS + jt * 16 + m]
                    = acc[jt][r] * inv[r];
            }
        }
    }
}

// ---------------- F2: ctx = P @ V (attn already normalized) ----------------
__launch_bounds__(256, 4)
__global__ void f2_kernel(const float* __restrict__ attn, const __bf16* __restrict__ Vt,
                          __bf16* __restrict__ ctx_bsd) {
    __shared__ __bf16 p_sh[16 * 520];

    int t = threadIdx.x;
    int l = t & 63, wv = t >> 6;
    int i0 = blockIdx.x, bh = blockIdx.y;

    const float* arow = attn + ((size_t)bh * SS + i0 * 16) * SS;
#pragma unroll
    for (int rr = 0; rr < 4; ++rr) {
        int row = wv * 4 + rr;
#pragma unroll
        for (int it = 0; it < 2; ++it) {
            int col = it * 256 + l * 4;
            f32x4 v = *(const f32x4*)(arow + (size_t)row * SS + col);
            bf16x4 pk = {(__bf16)v[0], (__bf16)v[1], (__bf16)v[2], (__bf16)v[3]};
            *(bf16x4*)&p_sh[row * 520 + col] = pk;
        }
    }
    __syncthreads();

    int m = l & 15, quad = l >> 4;
    f32x4 acc = {0.f, 0.f, 0.f, 0.f};
    const __bf16* vrow = Vt + ((size_t)bh * DK + wv * 16 + m) * SS + quad * 8;
    for (int k0 = 0; k0 < SS; k0 += 32) {
        bf16x8 aF = *(bf16x8*)&p_sh[m * 520 + k0 + quad * 8];
        bf16x8 bF = *(const bf16x8*)(vrow + k0);
        acc = __builtin_amdgcn_mfma_f32_16x16x32_bf16(aF, bF, acc, 0, 0, 0);
    }
    int b = bh >> 3, h = bh & 7;
#pragma unroll
    for (int r = 0; r < 4; ++r) {
        ctx_bsd[((size_t)(b * SS + i0 * 16 + quad * 4 + r)) * DD + h * DK + wv * 16 + m]
            = (__bf16)acc[r];
    }
}

// ---------------- K4: x = ctx @ Wo^T + bo + query; LayerNorm -> y ----------------
// grid 128 (16-row tiles), block (64,8). Wave w does n-tiles {w*4..w*4+3}.
__launch_bounds__(512, 2)
__global__ void k4_kernel(const __bf16* __restrict__ Xc, const __bf16* __restrict__ Wo_bf,
                          const float* __restrict__ bo, const float* __restrict__ query,
                          const float* __restrict__ gamma, const float* __restrict__ beta,
                          float* __restrict__ y) {
    __shared__ float xs[16 * 520];   // 33 KB

    int l = threadIdx.x, w = threadIdx.y;
    int rowb = blockIdx.x * 16;
    int m = l & 15, quad = l >> 4;

    f32x4 acc[4] = {{0,0,0,0},{0,0,0,0},{0,0,0,0},{0,0,0,0}};
    for (int k0 = 0; k0 < DD; k0 += 32) {
        bf16x8 a0 = *(const bf16x8*)(Xc + (size_t)(rowb + m) * DD + k0 + quad * 8);
#pragma unroll
        for (int tt = 0; tt < 4; ++tt) {
            int nrow = (w * 4 + tt) * 16 + m;
            bf16x8 b0 = *(const bf16x8*)(Wo_bf + (size_t)nrow * DD + k0 + quad * 8);
            acc[tt] = __builtin_amdgcn_mfma_f32_16x16x32_bf16(a0, b0, acc[tt], 0, 0, 0);
        }
    }
#pragma unroll
    for (int tt = 0; tt < 4; ++tt) {
        int col = (w * 4 + tt) * 16 + m;
        float bv = bo[col];
#pragma unroll
        for (int r = 0; r < 4; ++r) {
            int row = quad * 4 + r;
            xs[row * 520 + col] = acc[tt][r] + bv + query[(size_t)(rowb + row) * DD + col];
        }
    }
    __syncthreads();

    // LN: wave w -> rows 2w, 2w+1; lane l -> cols l*8..l*8+7
#pragma unroll
    for (int rr = 0; rr < 2; ++rr) {
        int row = w * 2 + rr;
        float v[8];
        *(f32x4*)(v) = *(f32x4*)&xs[row * 520 + l * 8];
        *(f32x4*)(v + 4) = *(f32x4*)&xs[row * 520 + l * 8 + 4];
        float s = 0.f;
#pragma unroll
        for (int e = 0; e < 8; ++e) s += v[e];
#pragma unroll
        for (int off = 32; off >= 1; off >>= 1) s += __shfl_xor(s, off);
        float mu = s * (1.f / DD);
        float sq = 0.f;
#pragma unroll
        for (int e = 0; e < 8; ++e) { v[e] -= mu; sq += v[e] * v[e]; }
#pragma unroll
        for (int off = 32; off >= 1; off >>= 1) sq += __shfl_xor(sq, off);
        float invs = rsqrtf(sq * (1.f / DD) + 1e-5f);
        f32x4 g0 = *(const f32x4*)(gamma + l * 8);
        f32x4 g1 = *(const f32x4*)(gamma + l * 8 + 4);
        f32x4 be0 = *(const f32x4*)(beta + l * 8);
        f32x4 be1 = *(const f32x4*)(beta + l * 8 + 4);
        f32x4 o0, o1;
#pragma unroll
        for (int e = 0; e < 4; ++e) o0[e] = v[e] * invs * g0[e] + be0[e];
#pragma unroll
        for (int e = 0; e < 4; ++e) o1[e] = v[e + 4] * invs * g1[e] + be1[e];
        *(f32x4*)(y + (size_t)(rowb + row) * DD + l * 8) = o0;
        *(f32x4*)(y + (size_t)(rowb + row) * DD + l * 8 + 4) = o1;
    }
}

extern "C" void kernel_launch(void* const* d_in, const int* in_sizes, int n_in,
                              void* d_out, int out_size, void* d_ws, size_t ws_size,
                              hipStream_t stream) {
    const float* query  = (const float*)d_in[0];
    const float* key    = (const float*)d_in[1];
    const float* value  = (const float*)d_in[2];
    const float* Wq     = (const float*)d_in[3];
    const float* bq     = (const float*)d_in[4];
    const float* Wk     = (const float*)d_in[5];
    const float* bk     = (const float*)d_in[6];
    const float* Wv     = (const float*)d_in[7];
    const float* bv     = (const float*)d_in[8];
    const float* Wo     = (const float*)d_in[9];
    const float* bo     = (const float*)d_in[10];
    const float* rtab   = (const float*)d_in[11];
    const float* gamma  = (const float*)d_in[12];
    const float* beta   = (const float*)d_in[13];
    const int*   mask   = (const int*)d_in[14];
    const int*   relpos = (const int*)d_in[15];

    float* out = (float*)d_out;
    float* y    = out;                        // [4,512,512]
    float* attn = out + (size_t)BB * SS * DD; // [4,8,512,512]

    char* wsb = (char*)d_ws;
    float*  Tm    = (float*)wsb;   wsb += 256;
    __bf16* Qbf   = (__bf16*)wsb;  wsb += (size_t)BB * HH * SS * DK * 2;
    __bf16* Kbf   = (__bf16*)wsb;  wsb += (size_t)BB * HH * SS * DK * 2;
    __bf16* Vtbf  = (__bf16*)wsb;  wsb += (size_t)BB * HH * DK * SS * 2;
    __bf16* ctxbf = (__bf16*)wsb;  wsb += (size_t)BB * SS * DD * 2;
    __bf16* Wo_bf = (__bf16*)wsb;  wsb += (size_t)DD * DD * 2;

    dim3 wblk(64, 4);
    hipLaunchKernelGGL(prep_kernel, dim3(32, 32, 4), wblk, 0, stream,
                       query, key, value, Wq, Wk, Wv, bq, bk, bv, Qbf, Kbf, Vtbf,
                       Wo, Wo_bf, rtab, Tm);

    hipLaunchKernelGGL(f1_kernel, dim3(SS / 8, BB), dim3(64, 8), 0, stream,
                       Qbf, Kbf, relpos, Tm, mask, attn);

    hipLaunchKernelGGL(f2_kernel, dim3(SS / 16, BB * HH), dim3(256), 0, stream,
                       attn, Vtbf, ctxbf);

    hipLaunchKernelGGL(k4_kernel, dim3((BB * SS) / 16), dim3(64, 8), 0, stream,
                       ctxbf, Wo_bf, bo, query, gamma, beta, y);
}